// Round 1
// baseline (2248.102 us; speedup 1.0000x reference)
//
#include <hip/hip_runtime.h>
#include <hip/hip_bf16.h>

// Problem constants (from reference)
#define NUM_USERS 100000
#define NUM_ITEMS 50000
#define N_NODES   150000   // NUM_USERS + NUM_ITEMS
#define EMB       64
#define NNZ       2400000
#define BATCH     16384
#define D_CAT     384      // EMB*3*2

// ---------------------------------------------------------------------------
// concat copy (float4): dst[i] = i < na4 ? a[i] : b[i-na4]
// ---------------------------------------------------------------------------
__global__ __launch_bounds__(256) void concat_copy4(const float4* __restrict__ a, int na4,
                                                    const float4* __restrict__ b, int nb4,
                                                    float4* __restrict__ dst) {
    int i = blockIdx.x * 256 + threadIdx.x;
    int n = na4 + nb4;
    if (i < n) dst[i] = (i < na4) ? a[i] : b[i - na4];
}

// ---------------------------------------------------------------------------
// SPMM (COO, atomic): h[r*64+lane] += v * x[c*64+lane]
// x is split across two arrays: col c < split -> xa[c], else xb[c-split]
// one wave (64 lanes) per nonzero edge
// ---------------------------------------------------------------------------
__global__ __launch_bounds__(256) void spmm_atomic(const int* __restrict__ rows,
                                                   const int* __restrict__ cols,
                                                   const float* __restrict__ vals,
                                                   const float* __restrict__ xa,
                                                   const float* __restrict__ xb,
                                                   int split,
                                                   float* __restrict__ h,
                                                   int nnz) {
    int t = blockIdx.x * 256 + threadIdx.x;
    int e = t >> 6;
    if (e >= nnz) return;
    int lane = t & 63;
    int r = rows[e];
    int c = cols[e];
    float v = vals[e];
    float xv = (c < split) ? xa[(size_t)c * EMB + lane]
                           : xb[(size_t)(c - split) * EMB + lane];
    __hip_atomic_fetch_add(&h[(size_t)r * EMB + lane], v * xv,
                           __ATOMIC_RELAXED, __HIP_MEMORY_SCOPE_AGENT);
}

// ---------------------------------------------------------------------------
// out[r][k] = relu( b[k] + sum_j h[r][j] * W[j][k] )   (W: 64x64 row-major)
// one wave per row; W staged in LDS; row broadcast via __shfl
// ---------------------------------------------------------------------------
__global__ __launch_bounds__(256) void gemm64_relu(const float* __restrict__ h,
                                                   const float* __restrict__ W,
                                                   const float* __restrict__ bia,
                                                   float* __restrict__ out,
                                                   int n_rows) {
    __shared__ float Wl[64 * 64];
    __shared__ float bl[64];
    int tid = threadIdx.x;
    for (int i = tid; i < 64 * 64; i += 256) Wl[i] = W[i];
    if (tid < 64) bl[tid] = bia[tid];
    __syncthreads();

    int lane = tid & 63;
    int wave = tid >> 6;                  // 0..3
    int gwave = blockIdx.x * 4 + wave;
    int nwaves = gridDim.x * 4;
    for (int r = gwave; r < n_rows; r += nwaves) {
        float hv = h[(size_t)r * 64 + lane];
        float acc = bl[lane];
#pragma unroll
        for (int j = 0; j < 64; ++j) {
            acc += __shfl(hv, j, 64) * Wl[j * 64 + lane];
        }
        out[(size_t)r * 64 + lane] = fmaxf(acc, 0.f);
    }
}

// ---------------------------------------------------------------------------
// Gather concatenated per-sample features:
// E[b][0:64]=uEmb[u], [64:128]=feat1[u], [128:192]=feat2[u],
// E[b][192:256]=iEmb[it], [256:320]=feat1[it+U], [320:384]=feat2[it+U]
// one block (384 threads) per batch row
// ---------------------------------------------------------------------------
__global__ __launch_bounds__(384) void gather_e(const int* __restrict__ userIdx,
                                                const int* __restrict__ itemIdx,
                                                const float* __restrict__ uEmb,
                                                const float* __restrict__ iEmb,
                                                const float* __restrict__ feat1,
                                                const float* __restrict__ feat2,
                                                float* __restrict__ E) {
    int b = blockIdx.x;
    int j = threadIdx.x;          // 0..383
    int half = j >= 192;          // 0: user, 1: item
    int jj = half ? (j - 192) : j;
    int seg = jj >> 6;            // 0: base emb, 1: layer1, 2: layer2
    int k = jj & 63;
    float v;
    if (half == 0) {
        int u = userIdx[b];
        if (seg == 0)      v = uEmb [(size_t)u * 64 + k];
        else if (seg == 1) v = feat1[(size_t)u * 64 + k];
        else               v = feat2[(size_t)u * 64 + k];
    } else {
        int it = itemIdx[b];
        if (seg == 0)      v = iEmb [(size_t)it * 64 + k];
        else if (seg == 1) v = feat1[(size_t)(it + NUM_USERS) * 64 + k];
        else               v = feat2[(size_t)(it + NUM_USERS) * 64 + k];
    }
    E[(size_t)b * D_CAT + j] = v;
}

// ---------------------------------------------------------------------------
// H1[r][k] = relu( b1[k] + sum_{j<384} E[r][j] * W1[j][k] )
// W1 staged in LDS in two 192x64 halves (48KB); 8 waves/block, 8 rows/wave
// grid must be exactly 256 blocks (256*8 waves * 8 rows = 16384)
// ---------------------------------------------------------------------------
__global__ __launch_bounds__(512) void mlp1(const float* __restrict__ E,
                                            const float* __restrict__ W1,
                                            const float* __restrict__ b1,
                                            float* __restrict__ H1) {
    __shared__ float Wl[192 * 64];   // 48 KB
    __shared__ float bl[64];
    int tid = threadIdx.x;
    int lane = tid & 63;
    int wave = tid >> 6;             // 0..7
    if (tid < 64) bl[tid] = b1[tid];
    for (int i = tid; i < 192 * 64; i += 512) Wl[i] = W1[i];
    __syncthreads();

    int g = blockIdx.x * 8 + wave;   // 0..2047
    float acc[8];
#pragma unroll
    for (int i = 0; i < 8; ++i) acc[i] = bl[lane];

#pragma unroll
    for (int half = 0; half < 2; ++half) {
        if (half) {
            __syncthreads();
            for (int i = tid; i < 192 * 64; i += 512) Wl[i] = W1[192 * 64 + i];
            __syncthreads();
        }
#pragma unroll
        for (int i = 0; i < 8; ++i) {
            int r = g * 8 + i;
            const float* Erow = E + (size_t)r * D_CAT + half * 192;
            float ev0 = Erow[lane];
            float ev1 = Erow[64 + lane];
            float ev2 = Erow[128 + lane];
            float a = acc[i];
#pragma unroll
            for (int j = 0; j < 64; ++j) {
                a += __shfl(ev0, j, 64) * Wl[j * 64 + lane];
                a += __shfl(ev1, j, 64) * Wl[(64 + j) * 64 + lane];
                a += __shfl(ev2, j, 64) * Wl[(128 + j) * 64 + lane];
            }
            acc[i] = a;
        }
    }
#pragma unroll
    for (int i = 0; i < 8; ++i)
        H1[(size_t)(g * 8 + i) * 64 + lane] = fmaxf(acc[i], 0.f);
}

// ---------------------------------------------------------------------------
// Fused last two layers: z = H1@W2 + b2 (no relu); out = z@W3 + b3
// One wave handles 2 rows (half-wave per row, 32 lanes = 32 cols of W2),
// then a half-wave shuffle reduction for the final dot with W3.
// ---------------------------------------------------------------------------
__global__ __launch_bounds__(256) void mlp23(const float* __restrict__ H1,
                                             const float* __restrict__ W2,
                                             const float* __restrict__ b2,
                                             const float* __restrict__ W3,
                                             const float* __restrict__ b3,
                                             float* __restrict__ out) {
    __shared__ float Wl[64 * 32];
    __shared__ float w3l[32];
    __shared__ float b2l[32];
    int tid = threadIdx.x;
    for (int i = tid; i < 64 * 32; i += 256) Wl[i] = W2[i];
    if (tid < 32) { w3l[tid] = W3[tid]; b2l[tid] = b2[tid]; }
    __syncthreads();

    int lane = tid & 63;
    int wave = tid >> 6;
    int half = lane >> 5;
    int k = lane & 31;
    int gpair = blockIdx.x * 4 + wave;
    int npairs = gridDim.x * 4;
    float b3v = b3[0];
    for (int p = gpair; p * 2 < BATCH; p += npairs) {
        int r = p * 2 + half;
        float acc = b2l[k];
#pragma unroll
        for (int j = 0; j < 64; ++j)
            acc += H1[(size_t)r * 64 + j] * Wl[j * 32 + k];
        acc = acc * w3l[k];
#pragma unroll
        for (int off = 16; off; off >>= 1)
            acc += __shfl_xor(acc, off, 64);
        if (k == 0) out[r] = acc + b3v;
    }
}

// ---------------------------------------------------------------------------
extern "C" void kernel_launch(void* const* d_in, const int* in_sizes, int n_in,
                              void* d_out, int out_size, void* d_ws, size_t ws_size,
                              hipStream_t stream) {
    const int*   userIdx = (const int*)  d_in[0];
    const int*   itemIdx = (const int*)  d_in[1];
    const int*   lap_rows= (const int*)  d_in[2];
    const int*   lap_cols= (const int*)  d_in[3];
    const float* lap_vals= (const float*)d_in[4];
    const float* uEmb    = (const float*)d_in[5];
    const float* iEmb    = (const float*)d_in[6];
    const float* gW0     = (const float*)d_in[7];
    const float* gb0     = (const float*)d_in[8];
    const float* gW1     = (const float*)d_in[9];
    const float* gb1     = (const float*)d_in[10];
    const float* W1      = (const float*)d_in[11];
    const float* b1      = (const float*)d_in[12];
    const float* W2      = (const float*)d_in[13];
    const float* b2      = (const float*)d_in[14];
    const float* W3      = (const float*)d_in[15];
    const float* b3      = (const float*)d_in[16];
    float* out = (float*)d_out;

    const size_t NF = (size_t)N_NODES * EMB;          // 9,600,000 floats
    float* ws    = (float*)d_ws;
    float* feat1 = ws;                                 // [N_NODES, 64]
    float* feat2 = ws + NF;                            // [N_NODES, 64]
    float* h     = ws + 2 * NF;                        // [N_NODES, 64] scratch
    // After layer 2 GEMM, h region is reused:
    float* E     = h;                                  // [BATCH, 384] = 6,291,456 floats
    float* H1    = h + (size_t)BATCH * D_CAT;          // [BATCH, 64]
    // (E + H1 = 7,340,032 floats <= NF = 9,600,000)

    const int n4_feat  = (int)(NF / 4);                // 2,400,000 float4
    const int na4_user = NUM_USERS * EMB / 4;          // 1,600,000
    const int nb4_item = NUM_ITEMS * EMB / 4;          //   800,000
    const int copy_grid = (n4_feat + 255) / 256;
    const int spmm_grid = (NNZ * 64) / 256;            // 600,000 blocks

    // ---- Layer 1: h = feat0 (=concat(uEmb,iEmb)); h += L @ feat0; feat1 = relu(h@gW0+gb0)
    concat_copy4<<<copy_grid, 256, 0, stream>>>((const float4*)uEmb, na4_user,
                                                (const float4*)iEmb, nb4_item,
                                                (float4*)h);
    spmm_atomic<<<spmm_grid, 256, 0, stream>>>(lap_rows, lap_cols, lap_vals,
                                               uEmb, iEmb, NUM_USERS, h, NNZ);
    gemm64_relu<<<2048, 256, 0, stream>>>(h, gW0, gb0, feat1, N_NODES);

    // ---- Layer 2: h = feat1; h += L @ feat1; feat2 = relu(h@gW1+gb1)
    concat_copy4<<<copy_grid, 256, 0, stream>>>((const float4*)feat1, n4_feat,
                                                (const float4*)feat1, 0,
                                                (float4*)h);
    spmm_atomic<<<spmm_grid, 256, 0, stream>>>(lap_rows, lap_cols, lap_vals,
                                               feat1, feat1, N_NODES, h, NNZ);
    gemm64_relu<<<2048, 256, 0, stream>>>(h, gW1, gb1, feat2, N_NODES);

    // ---- Gather per-sample concatenated features
    gather_e<<<BATCH, 384, 0, stream>>>(userIdx, itemIdx, uEmb, iEmb, feat1, feat2, E);

    // ---- MLP
    mlp1<<<256, 512, 0, stream>>>(E, W1, b1, H1);
    mlp23<<<512, 256, 0, stream>>>(H1, W2, b2, W3, b3, out);
}

// Round 2
// 1489.852 us; speedup vs baseline: 1.5089x; 1.5089x over previous
//
#include <hip/hip_runtime.h>
#include <hip/hip_bf16.h>

// Problem constants (from reference)
#define NUM_USERS 100000
#define NUM_ITEMS 50000
#define N_NODES   150000   // NUM_USERS + NUM_ITEMS
#define EMB       64
#define NNZ       2400000
#define BATCH     16384
#define D_CAT     384      // EMB*3*2

// ---------------------------------------------------------------------------
// concat copy (float4): dst[i] = i < na4 ? a[i] : b[i-na4]
// ---------------------------------------------------------------------------
__global__ __launch_bounds__(256) void concat_copy4(const float4* __restrict__ a, int na4,
                                                    const float4* __restrict__ b, int nb4,
                                                    float4* __restrict__ dst) {
    int i = blockIdx.x * 256 + threadIdx.x;
    int n = na4 + nb4;
    if (i < n) dst[i] = (i < na4) ? a[i] : b[i - na4];
}

// ---------------------------------------------------------------------------
// SPMM (COO, atomic): h[r*64+lane] += v * x[c*64+lane]
// x is split across two arrays: col c < split -> xa[c], else xb[c-split]
// one wave (64 lanes) per nonzero edge
// ---------------------------------------------------------------------------
__global__ __launch_bounds__(256) void spmm_atomic(const int* __restrict__ rows,
                                                   const int* __restrict__ cols,
                                                   const float* __restrict__ vals,
                                                   const float* __restrict__ xa,
                                                   const float* __restrict__ xb,
                                                   int split,
                                                   float* __restrict__ h,
                                                   int nnz) {
    int t = blockIdx.x * 256 + threadIdx.x;
    int e = t >> 6;
    if (e >= nnz) return;
    int lane = t & 63;
    int r = rows[e];
    int c = cols[e];
    float v = vals[e];
    float xv = (c < split) ? xa[(size_t)c * EMB + lane]
                           : xb[(size_t)(c - split) * EMB + lane];
    __hip_atomic_fetch_add(&h[(size_t)r * EMB + lane], v * xv,
                           __ATOMIC_RELAXED, __HIP_MEMORY_SCOPE_AGENT);
}

// ---------------------------------------------------------------------------
// out[r][c] = relu( b[c] + sum_{k<K} X[r][k] * W[k][c] ),  64 output cols.
// Register-blocked: 4 waves/block, each wave owns 16 rows; lane = col.
// W staged in LDS in <=128-row chunks (<=32 KB); X row values are
// wave-uniform float4 broadcast loads (L1-served, no LDS, no shuffles).
// ~60 VGPRs, no spill (the round-1 mlp1 spilled ~1.2 GB of scratch).
// ---------------------------------------------------------------------------
template<int K>
__global__ __launch_bounds__(256) void gemm_k_relu(const float* __restrict__ X,
                                                   const float* __restrict__ W,
                                                   const float* __restrict__ bia,
                                                   float* __restrict__ out,
                                                   int n_rows) {
    constexpr int CHUNK = (K < 128) ? K : 128;
    __shared__ float Wl[CHUNK * 64];
    int tid = threadIdx.x;
    int lane = tid & 63;
    int wave = tid >> 6;                 // 0..3
    int r0 = blockIdx.x * 64 + wave * 16;
    int last = n_rows - 1;

    // clamped row base pointers (avoids per-iteration bounds branches)
    const float* rowp[16];
#pragma unroll
    for (int i = 0; i < 16; ++i) {
        int r = r0 + i;
        r = r > last ? last : r;
        rowp[i] = X + (size_t)r * K;
    }

    float acc[16];
    float bv = bia[lane];
#pragma unroll
    for (int i = 0; i < 16; ++i) acc[i] = bv;

    for (int k0 = 0; k0 < K; k0 += CHUNK) {
        if (k0) __syncthreads();
        for (int i = tid; i < CHUNK * 64; i += 256) Wl[i] = W[k0 * 64 + i];
        __syncthreads();
#pragma unroll 1
        for (int k = 0; k < CHUNK; k += 4) {
            float w0 = Wl[(k + 0) * 64 + lane];
            float w1 = Wl[(k + 1) * 64 + lane];
            float w2 = Wl[(k + 2) * 64 + lane];
            float w3 = Wl[(k + 3) * 64 + lane];
#pragma unroll
            for (int i = 0; i < 16; ++i) {
                float4 e = *(const float4*)(rowp[i] + k0 + k);
                acc[i] = fmaf(e.x, w0, acc[i]);
                acc[i] = fmaf(e.y, w1, acc[i]);
                acc[i] = fmaf(e.z, w2, acc[i]);
                acc[i] = fmaf(e.w, w3, acc[i]);
            }
        }
    }

#pragma unroll
    for (int i = 0; i < 16; ++i) {
        int r = r0 + i;
        if (r < n_rows) out[(size_t)r * 64 + lane] = fmaxf(acc[i], 0.f);
    }
}

// ---------------------------------------------------------------------------
// Gather concatenated per-sample features:
// E[b][0:64]=uEmb[u], [64:128]=feat1[u], [128:192]=feat2[u],
// E[b][192:256]=iEmb[it], [256:320]=feat1[it+U], [320:384]=feat2[it+U]
// one block (384 threads) per batch row
// ---------------------------------------------------------------------------
__global__ __launch_bounds__(384) void gather_e(const int* __restrict__ userIdx,
                                                const int* __restrict__ itemIdx,
                                                const float* __restrict__ uEmb,
                                                const float* __restrict__ iEmb,
                                                const float* __restrict__ feat1,
                                                const float* __restrict__ feat2,
                                                float* __restrict__ E) {
    int b = blockIdx.x;
    int j = threadIdx.x;          // 0..383
    int half = j >= 192;          // 0: user, 1: item
    int jj = half ? (j - 192) : j;
    int seg = jj >> 6;            // 0: base emb, 1: layer1, 2: layer2
    int k = jj & 63;
    float v;
    if (half == 0) {
        int u = userIdx[b];
        if (seg == 0)      v = uEmb [(size_t)u * 64 + k];
        else if (seg == 1) v = feat1[(size_t)u * 64 + k];
        else               v = feat2[(size_t)u * 64 + k];
    } else {
        int it = itemIdx[b];
        if (seg == 0)      v = iEmb [(size_t)it * 64 + k];
        else if (seg == 1) v = feat1[(size_t)(it + NUM_USERS) * 64 + k];
        else               v = feat2[(size_t)(it + NUM_USERS) * 64 + k];
    }
    E[(size_t)b * D_CAT + j] = v;
}

// ---------------------------------------------------------------------------
// Fused last two layers: z = H1@W2 + b2 (no relu); out = z@W3 + b3
// One wave handles 2 rows (half-wave per row, 32 lanes = 32 cols of W2),
// then a half-wave shuffle reduction for the final dot with W3.
// ---------------------------------------------------------------------------
__global__ __launch_bounds__(256) void mlp23(const float* __restrict__ H1,
                                             const float* __restrict__ W2,
                                             const float* __restrict__ b2,
                                             const float* __restrict__ W3,
                                             const float* __restrict__ b3,
                                             float* __restrict__ out) {
    __shared__ float Wl[64 * 32];
    __shared__ float w3l[32];
    __shared__ float b2l[32];
    int tid = threadIdx.x;
    for (int i = tid; i < 64 * 32; i += 256) Wl[i] = W2[i];
    if (tid < 32) { w3l[tid] = W3[tid]; b2l[tid] = b2[tid]; }
    __syncthreads();

    int lane = tid & 63;
    int wave = tid >> 6;
    int half = lane >> 5;
    int k = lane & 31;
    int gpair = blockIdx.x * 4 + wave;
    int npairs = gridDim.x * 4;
    float b3v = b3[0];
    for (int p = gpair; p * 2 < BATCH; p += npairs) {
        int r = p * 2 + half;
        float acc = b2l[k];
#pragma unroll
        for (int j = 0; j < 64; ++j)
            acc += H1[(size_t)r * 64 + j] * Wl[j * 32 + k];
        acc = acc * w3l[k];
#pragma unroll
        for (int off = 16; off; off >>= 1)
            acc += __shfl_xor(acc, off, 64);
        if (k == 0) out[r] = acc + b3v;
    }
}

// ---------------------------------------------------------------------------
extern "C" void kernel_launch(void* const* d_in, const int* in_sizes, int n_in,
                              void* d_out, int out_size, void* d_ws, size_t ws_size,
                              hipStream_t stream) {
    const int*   userIdx = (const int*)  d_in[0];
    const int*   itemIdx = (const int*)  d_in[1];
    const int*   lap_rows= (const int*)  d_in[2];
    const int*   lap_cols= (const int*)  d_in[3];
    const float* lap_vals= (const float*)d_in[4];
    const float* uEmb    = (const float*)d_in[5];
    const float* iEmb    = (const float*)d_in[6];
    const float* gW0     = (const float*)d_in[7];
    const float* gb0     = (const float*)d_in[8];
    const float* gW1     = (const float*)d_in[9];
    const float* gb1     = (const float*)d_in[10];
    const float* W1      = (const float*)d_in[11];
    const float* b1      = (const float*)d_in[12];
    const float* W2      = (const float*)d_in[13];
    const float* b2      = (const float*)d_in[14];
    const float* W3      = (const float*)d_in[15];
    const float* b3      = (const float*)d_in[16];
    float* out = (float*)d_out;

    const size_t NF = (size_t)N_NODES * EMB;          // 9,600,000 floats
    float* ws    = (float*)d_ws;
    float* feat1 = ws;                                 // [N_NODES, 64]
    float* feat2 = ws + NF;                            // [N_NODES, 64]
    float* h     = ws + 2 * NF;                        // [N_NODES, 64] scratch
    // After layer 2 GEMM, h region is reused:
    float* E     = h;                                  // [BATCH, 384]
    float* H1    = h + (size_t)BATCH * D_CAT;          // [BATCH, 64]

    const int n4_feat  = (int)(NF / 4);                // 2,400,000 float4
    const int na4_user = NUM_USERS * EMB / 4;
    const int nb4_item = NUM_ITEMS * EMB / 4;
    const int copy_grid = (n4_feat + 255) / 256;
    const int spmm_grid = (NNZ * 64) / 256;            // 600,000 blocks
    const int gemm_grid = (N_NODES + 63) / 64;         // 2344

    // ---- Layer 1: h = feat0; h += L @ feat0; feat1 = relu(h@gW0+gb0)
    concat_copy4<<<copy_grid, 256, 0, stream>>>((const float4*)uEmb, na4_user,
                                                (const float4*)iEmb, nb4_item,
                                                (float4*)h);
    spmm_atomic<<<spmm_grid, 256, 0, stream>>>(lap_rows, lap_cols, lap_vals,
                                               uEmb, iEmb, NUM_USERS, h, NNZ);
    gemm_k_relu<64><<<gemm_grid, 256, 0, stream>>>(h, gW0, gb0, feat1, N_NODES);

    // ---- Layer 2: h = feat1; h += L @ feat1; feat2 = relu(h@gW1+gb1)
    concat_copy4<<<copy_grid, 256, 0, stream>>>((const float4*)feat1, n4_feat,
                                                (const float4*)feat1, 0,
                                                (float4*)h);
    spmm_atomic<<<spmm_grid, 256, 0, stream>>>(lap_rows, lap_cols, lap_vals,
                                               feat1, feat1, NUM_USERS + NUM_ITEMS,
                                               h, NNZ);
    gemm_k_relu<64><<<gemm_grid, 256, 0, stream>>>(h, gW1, gb1, feat2, N_NODES);

    // ---- Gather per-sample concatenated features
    gather_e<<<BATCH, 384, 0, stream>>>(userIdx, itemIdx, uEmb, iEmb, feat1, feat2, E);

    // ---- MLP
    gemm_k_relu<384><<<(BATCH + 63) / 64, 256, 0, stream>>>(E, W1, b1, H1, BATCH);
    mlp23<<<512, 256, 0, stream>>>(H1, W2, b2, W3, b3, out);
}

// Round 3
// 924.106 us; speedup vs baseline: 2.4327x; 1.6122x over previous
//
#include <hip/hip_runtime.h>
#include <hip/hip_bf16.h>

// Problem constants (from reference)
#define NUM_USERS 100000
#define NUM_ITEMS 50000
#define N_NODES   150000   // NUM_USERS + NUM_ITEMS
#define EMB       64
#define NNZ       2400000
#define BATCH     16384
#define D_CAT     384      // EMB*3*2

// ---------------------------------------------------------------------------
// CSR build step 1: histogram of row indices. cnt must be zeroed first.
// ---------------------------------------------------------------------------
__global__ __launch_bounds__(256) void hist_rows(const int* __restrict__ rows,
                                                 int* __restrict__ cnt, int nnz) {
    int i = blockIdx.x * 256 + threadIdx.x;
    if (i < nnz) atomicAdd(&cnt[rows[i]], 1);
}

// ---------------------------------------------------------------------------
// CSR build step 2a: per-block (1024-elem) exclusive scan of cnt -> partial,
// block totals -> blockSums. partial stored into row_ptr (temporarily).
// ---------------------------------------------------------------------------
__global__ __launch_bounds__(1024) void scan1(const int* __restrict__ cnt,
                                              int* __restrict__ partial,
                                              int* __restrict__ blockSums, int n) {
    __shared__ int s[1024];
    int t = threadIdx.x;
    int i = blockIdx.x * 1024 + t;
    int x = (i < n) ? cnt[i] : 0;
    s[t] = x;
    __syncthreads();
#pragma unroll
    for (int off = 1; off < 1024; off <<= 1) {
        int v = (t >= off) ? s[t - off] : 0;
        __syncthreads();
        s[t] += v;
        __syncthreads();
    }
    if (i < n) partial[i] = s[t] - x;          // exclusive within block
    if (t == 1023) blockSums[blockIdx.x] = s[t];
}

// ---------------------------------------------------------------------------
// CSR build step 2b: single-block exclusive scan of blockSums (in place).
// ---------------------------------------------------------------------------
__global__ __launch_bounds__(1024) void scan2(int* __restrict__ blockSums, int nb) {
    __shared__ int s[1024];
    int t = threadIdx.x;
    int x = (t < nb) ? blockSums[t] : 0;
    s[t] = x;
    __syncthreads();
#pragma unroll
    for (int off = 1; off < 1024; off <<= 1) {
        int v = (t >= off) ? s[t - off] : 0;
        __syncthreads();
        s[t] += v;
        __syncthreads();
    }
    if (t < nb) blockSums[t] = s[t] - x;       // exclusive
}

// ---------------------------------------------------------------------------
// CSR build step 2c: row_ptr[i] = partial[i] + blockOffs[blk]; offs copy too.
// Also writes row_ptr[n] = nnz.
// ---------------------------------------------------------------------------
__global__ __launch_bounds__(1024) void scan3(int* __restrict__ row_ptr,
                                              int* __restrict__ offs,
                                              const int* __restrict__ blockSums,
                                              int n, int nnz) {
    int t = threadIdx.x;
    int i = blockIdx.x * 1024 + t;
    if (i < n) {
        int v = row_ptr[i] + blockSums[blockIdx.x];
        row_ptr[i] = v;
        offs[i] = v;
    }
    if (i == 0) row_ptr[n] = nnz;
}

// ---------------------------------------------------------------------------
// CSR build step 3: scatter (col, val) pairs into row-sorted packed array.
// ---------------------------------------------------------------------------
__global__ __launch_bounds__(256) void scatter_edges(const int* __restrict__ rows,
                                                     const int* __restrict__ cols,
                                                     const float* __restrict__ vals,
                                                     int* __restrict__ offs,
                                                     int2* __restrict__ packed, int nnz) {
    int i = blockIdx.x * 256 + threadIdx.x;
    if (i >= nnz) return;
    int r = rows[i];
    int pos = atomicAdd(&offs[r], 1);
    packed[pos] = make_int2(cols[i], __float_as_int(vals[i]));
}

// ---------------------------------------------------------------------------
// Fused layer: out[r] = relu( ((L+I)X)[r] @ W + b ), one wave per row.
// acc[lane] = X[r][lane] + sum_edges v * X[c][lane]   (register accumulate,
// single coalesced store — replaces the 614 MB of atomic write-through).
// Then 64-step shuffle-broadcast GEMM against LDS-staged W (64x64).
// X split across xa/xb at `split` (layer 1: uEmb/iEmb; layer 2: feat1 only).
// ---------------------------------------------------------------------------
__global__ __launch_bounds__(256) void spmm_csr_gemm_relu(
        const int* __restrict__ row_ptr, const int2* __restrict__ packed,
        const float* __restrict__ xa, const float* __restrict__ xb, int split,
        const float* __restrict__ W, const float* __restrict__ bias,
        float* __restrict__ out, int n_rows) {
    __shared__ float Wl[64 * 64];
    __shared__ float bl[64];
    int tid = threadIdx.x;
    for (int i = tid; i < 64 * 64; i += 256) Wl[i] = W[i];
    if (tid < 64) bl[tid] = bias[tid];
    __syncthreads();

    int lane = tid & 63;
    int wave = tid >> 6;
    int r = blockIdx.x * 4 + wave;
    if (r >= n_rows) return;

    // self loop
    const float* selfp = (r < split) ? xa + (size_t)r * 64
                                     : xb + (size_t)(r - split) * 64;
    float acc = selfp[lane];

    int e = row_ptr[r];
    int end = row_ptr[r + 1];
    // 4-deep software pipeline over edges
    for (; e + 4 <= end; e += 4) {
        int2 p0 = packed[e + 0];
        int2 p1 = packed[e + 1];
        int2 p2 = packed[e + 2];
        int2 p3 = packed[e + 3];
        const float* g0 = (p0.x < split) ? xa + (size_t)p0.x * 64 : xb + (size_t)(p0.x - split) * 64;
        const float* g1 = (p1.x < split) ? xa + (size_t)p1.x * 64 : xb + (size_t)(p1.x - split) * 64;
        const float* g2 = (p2.x < split) ? xa + (size_t)p2.x * 64 : xb + (size_t)(p2.x - split) * 64;
        const float* g3 = (p3.x < split) ? xa + (size_t)p3.x * 64 : xb + (size_t)(p3.x - split) * 64;
        float x0 = g0[lane];
        float x1 = g1[lane];
        float x2 = g2[lane];
        float x3 = g3[lane];
        acc = fmaf(__int_as_float(p0.y), x0, acc);
        acc = fmaf(__int_as_float(p1.y), x1, acc);
        acc = fmaf(__int_as_float(p2.y), x2, acc);
        acc = fmaf(__int_as_float(p3.y), x3, acc);
    }
    for (; e < end; ++e) {
        int2 p = packed[e];
        const float* g = (p.x < split) ? xa + (size_t)p.x * 64 : xb + (size_t)(p.x - split) * 64;
        acc = fmaf(__int_as_float(p.y), g[lane], acc);
    }

    // fused 64x64 GEMM + bias + relu: out[lane] = sum_j acc_j * W[j][lane]
    float o = bl[lane];
#pragma unroll
    for (int j = 0; j < 64; ++j)
        o = fmaf(__shfl(acc, j, 64), Wl[j * 64 + lane], o);
    out[(size_t)r * 64 + lane] = fmaxf(o, 0.f);
}

// ---------------------------------------------------------------------------
// out[r][c] = relu( b[c] + sum_{k<K} X[r][k] * W[k][c] ),  64 output cols.
// Register-blocked: 4 waves/block, each wave owns 16 rows; lane = col.
// ---------------------------------------------------------------------------
template<int K>
__global__ __launch_bounds__(256) void gemm_k_relu(const float* __restrict__ X,
                                                   const float* __restrict__ W,
                                                   const float* __restrict__ bia,
                                                   float* __restrict__ out,
                                                   int n_rows) {
    constexpr int CHUNK = (K < 128) ? K : 128;
    __shared__ float Wl[CHUNK * 64];
    int tid = threadIdx.x;
    int lane = tid & 63;
    int wave = tid >> 6;                 // 0..3
    int r0 = blockIdx.x * 64 + wave * 16;
    int last = n_rows - 1;

    const float* rowp[16];
#pragma unroll
    for (int i = 0; i < 16; ++i) {
        int r = r0 + i;
        r = r > last ? last : r;
        rowp[i] = X + (size_t)r * K;
    }

    float acc[16];
    float bv = bia[lane];
#pragma unroll
    for (int i = 0; i < 16; ++i) acc[i] = bv;

    for (int k0 = 0; k0 < K; k0 += CHUNK) {
        if (k0) __syncthreads();
        for (int i = tid; i < CHUNK * 64; i += 256) Wl[i] = W[k0 * 64 + i];
        __syncthreads();
#pragma unroll 1
        for (int k = 0; k < CHUNK; k += 4) {
            float w0 = Wl[(k + 0) * 64 + lane];
            float w1 = Wl[(k + 1) * 64 + lane];
            float w2 = Wl[(k + 2) * 64 + lane];
            float w3 = Wl[(k + 3) * 64 + lane];
#pragma unroll
            for (int i = 0; i < 16; ++i) {
                float4 e = *(const float4*)(rowp[i] + k0 + k);
                acc[i] = fmaf(e.x, w0, acc[i]);
                acc[i] = fmaf(e.y, w1, acc[i]);
                acc[i] = fmaf(e.z, w2, acc[i]);
                acc[i] = fmaf(e.w, w3, acc[i]);
            }
        }
    }

#pragma unroll
    for (int i = 0; i < 16; ++i) {
        int r = r0 + i;
        if (r < n_rows) out[(size_t)r * 64 + lane] = fmaxf(acc[i], 0.f);
    }
}

// ---------------------------------------------------------------------------
// Gather concatenated per-sample features (one block of 384 per batch row)
// ---------------------------------------------------------------------------
__global__ __launch_bounds__(384) void gather_e(const int* __restrict__ userIdx,
                                                const int* __restrict__ itemIdx,
                                                const float* __restrict__ uEmb,
                                                const float* __restrict__ iEmb,
                                                const float* __restrict__ feat1,
                                                const float* __restrict__ feat2,
                                                float* __restrict__ E) {
    int b = blockIdx.x;
    int j = threadIdx.x;          // 0..383
    int half = j >= 192;
    int jj = half ? (j - 192) : j;
    int seg = jj >> 6;
    int k = jj & 63;
    float v;
    if (half == 0) {
        int u = userIdx[b];
        if (seg == 0)      v = uEmb [(size_t)u * 64 + k];
        else if (seg == 1) v = feat1[(size_t)u * 64 + k];
        else               v = feat2[(size_t)u * 64 + k];
    } else {
        int it = itemIdx[b];
        if (seg == 0)      v = iEmb [(size_t)it * 64 + k];
        else if (seg == 1) v = feat1[(size_t)(it + NUM_USERS) * 64 + k];
        else               v = feat2[(size_t)(it + NUM_USERS) * 64 + k];
    }
    E[(size_t)b * D_CAT + j] = v;
}

// ---------------------------------------------------------------------------
// Fused last two layers: z = H1@W2 + b2 (no relu); out = z@W3 + b3
// ---------------------------------------------------------------------------
__global__ __launch_bounds__(256) void mlp23(const float* __restrict__ H1,
                                             const float* __restrict__ W2,
                                             const float* __restrict__ b2,
                                             const float* __restrict__ W3,
                                             const float* __restrict__ b3,
                                             float* __restrict__ out) {
    __shared__ float Wl[64 * 32];
    __shared__ float w3l[32];
    __shared__ float b2l[32];
    int tid = threadIdx.x;
    for (int i = tid; i < 64 * 32; i += 256) Wl[i] = W2[i];
    if (tid < 32) { w3l[tid] = W3[tid]; b2l[tid] = b2[tid]; }
    __syncthreads();

    int lane = tid & 63;
    int wave = tid >> 6;
    int half = lane >> 5;
    int k = lane & 31;
    int gpair = blockIdx.x * 4 + wave;
    int npairs = gridDim.x * 4;
    float b3v = b3[0];
    for (int p = gpair; p * 2 < BATCH; p += npairs) {
        int r = p * 2 + half;
        float acc = b2l[k];
#pragma unroll
        for (int j = 0; j < 64; ++j)
            acc += H1[(size_t)r * 64 + j] * Wl[j * 32 + k];
        acc = acc * w3l[k];
#pragma unroll
        for (int off = 16; off; off >>= 1)
            acc += __shfl_xor(acc, off, 64);
        if (k == 0) out[r] = acc + b3v;
    }
}

// ---------------------------------------------------------------------------
extern "C" void kernel_launch(void* const* d_in, const int* in_sizes, int n_in,
                              void* d_out, int out_size, void* d_ws, size_t ws_size,
                              hipStream_t stream) {
    const int*   userIdx = (const int*)  d_in[0];
    const int*   itemIdx = (const int*)  d_in[1];
    const int*   lap_rows= (const int*)  d_in[2];
    const int*   lap_cols= (const int*)  d_in[3];
    const float* lap_vals= (const float*)d_in[4];
    const float* uEmb    = (const float*)d_in[5];
    const float* iEmb    = (const float*)d_in[6];
    const float* gW0     = (const float*)d_in[7];
    const float* gb0     = (const float*)d_in[8];
    const float* gW1     = (const float*)d_in[9];
    const float* gb1     = (const float*)d_in[10];
    const float* W1      = (const float*)d_in[11];
    const float* b1      = (const float*)d_in[12];
    const float* W2      = (const float*)d_in[13];
    const float* b2      = (const float*)d_in[14];
    const float* W3      = (const float*)d_in[15];
    const float* b3      = (const float*)d_in[16];
    float* out = (float*)d_out;

    const size_t NF = (size_t)N_NODES * EMB;          // 9,600,000 floats
    float* ws    = (float*)d_ws;
    float* feat1 = ws;                                 // [N_NODES, 64]
    float* feat2 = ws + NF;                            // [N_NODES, 64]
    // region 3 (38.4 MB): CSR arrays first, later reused for E/H1
    int*   i3      = (int*)(ws + 2 * NF);
    int2*  packed  = (int2*)i3;                        // 2*NNZ ints (19.2 MB)
    int*   row_ptr = i3 + 2 * NNZ;                     // N_NODES+1 ints
    int*   offs    = i3 + 2 * NNZ + 160000;            // N_NODES ints (doubles as cnt)
    int*   bsums   = i3 + 2 * NNZ + 320000;            // 1024 ints
    // E/H1 overwrite the CSR region only after its last use (gather_e onward)
    float* E  = (float*)i3;                            // [BATCH, 384]
    float* H1 = (float*)i3 + (size_t)BATCH * D_CAT;    // [BATCH, 64]

    const int SCAN_NB = (N_NODES + 1023) / 1024;       // 147
    const int edge_grid = (NNZ + 255) / 256;           // 9375
    const int spmm_grid = (N_NODES + 3) / 4;           // 37500

    // ---- Build CSR (used by both layers)
    hipMemsetAsync(offs, 0, N_NODES * sizeof(int), stream);
    hist_rows<<<edge_grid, 256, 0, stream>>>(lap_rows, offs, NNZ);
    scan1<<<SCAN_NB, 1024, 0, stream>>>(offs, row_ptr, bsums, N_NODES);
    scan2<<<1, 1024, 0, stream>>>(bsums, SCAN_NB);
    scan3<<<SCAN_NB, 1024, 0, stream>>>(row_ptr, offs, bsums, N_NODES, NNZ);
    scatter_edges<<<edge_grid, 256, 0, stream>>>(lap_rows, lap_cols, lap_vals,
                                                 offs, packed, NNZ);

    // ---- Layer 1: feat1 = relu( ((L+I)@feat0) @ gW0 + gb0 ),  feat0 = [uEmb;iEmb]
    spmm_csr_gemm_relu<<<spmm_grid, 256, 0, stream>>>(row_ptr, packed,
                                                      uEmb, iEmb, NUM_USERS,
                                                      gW0, gb0, feat1, N_NODES);
    // ---- Layer 2: feat2 = relu( ((L+I)@feat1) @ gW1 + gb1 )
    spmm_csr_gemm_relu<<<spmm_grid, 256, 0, stream>>>(row_ptr, packed,
                                                      feat1, feat1, N_NODES,
                                                      gW1, gb1, feat2, N_NODES);

    // ---- Gather per-sample concatenated features (E overwrites CSR region)
    gather_e<<<BATCH, 384, 0, stream>>>(userIdx, itemIdx, uEmb, iEmb, feat1, feat2, E);

    // ---- MLP
    gemm_k_relu<384><<<(BATCH + 63) / 64, 256, 0, stream>>>(E, W1, b1, H1, BATCH);
    mlp23<<<512, 256, 0, stream>>>(H1, W2, b2, W3, b3, out);
}